// Round 6
// baseline (330.956 us; speedup 1.0000x reference)
//
#include <hip/hip_runtime.h>
#include <hip/hip_bf16.h>
#include <math.h>

// Problem constants
#define S_LEN 1024
#define HDIM  2880
#define NH    64
#define NKV   8
#define HD    64
#define QKV_N ((NH + 2*NKV) * HD)   // 5120
#define O_K   (NH * HD)             // 4096
#define SCALE 0.125f                // HD^-0.5

typedef _Float16 f16x8 __attribute__((ext_vector_type(8)));
typedef _Float16 f16x4 __attribute__((ext_vector_type(4)));
typedef float    f32x4 __attribute__((ext_vector_type(4)));

// ---------------------------------------------------------------------------
// f32 -> f16 convert (hidden only now; n4 = float4 count)
// ---------------------------------------------------------------------------
__global__ __launch_bounds__(256) void cvt_f32_f16(const float* __restrict__ src,
                                                   _Float16* __restrict__ dst, int n4) {
    const int stride = gridDim.x * blockDim.x;
    for (int i = blockIdx.x * blockDim.x + threadIdx.x; i < n4; i += stride) {
        const float4 v = ((const float4*)src)[i];
        f16x4 p;
        p[0] = (_Float16)v.x; p[1] = (_Float16)v.y;
        p[2] = (_Float16)v.z; p[3] = (_Float16)v.w;
        ((f16x4*)dst)[i] = p;
    }
}

// ---------------------------------------------------------------------------
// Split-K MFMA GEMM: Cpart[z][M,N] = A[M,K slice](f16) * B[N,K](f32, fused
// convert)^T. 128x128 tile, BK=32, 256 thr = 4 waves (64x64 quadrant each,
// 4x4 16x16x32 f16 MFMAs). Epilogue goes through LDS (stride 68 f16) so
// global stores are coalesced 16B chunks. CT = f16 partials or f32 direct.
// ---------------------------------------------------------------------------
#define CSTR 68
template<typename CT>
__global__ __launch_bounds__(256) void gemm_f16(const _Float16* __restrict__ A,
                                                const float* __restrict__ B,
                                                CT* __restrict__ C,
                                                int M, int N, int K) {
    __shared__ __align__(16) _Float16 sh[128 * CSTR];   // 17408 B
    _Float16* As = sh;              // 128*32
    _Float16* Bs = sh + 4096;       // 128*32

    const int tid  = threadIdx.x;
    const int lane = tid & 63;
    const int wave = tid >> 6;
    const int wr   = wave >> 1;
    const int wc   = wave & 1;
    const int quad = lane >> 4;
    const int fr   = lane & 15;
    const int ks   = quad * 8;
    const int row0 = blockIdx.y * 128;
    const int col0 = blockIdx.x * 128;

    const int klen = K / (int)gridDim.z;
    const int kb   = (int)blockIdx.z * klen;
    CT* Cp = C + (size_t)blockIdx.z * M * N;

    f32x4 acc[4][4] = {};

    for (int k0 = kb; k0 < kb + klen; k0 += 32) {
        __syncthreads();
        // ---- A tile: 128x32 f16 via async direct-to-LDS ----
#pragma unroll
        for (int it = 0; it < 2; ++it) {
            const int cbase = it * 256 + wave * 64;
            const int ci = cbase + lane;
            const int r  = ci >> 2;
            const int ch = ci & 3;
            const _Float16* gp = A + (size_t)(row0 + r) * K + k0 + ch * 8;
            __builtin_amdgcn_global_load_lds(
                (const __attribute__((address_space(1))) void*)gp,
                (__attribute__((address_space(3))) void*)(As + (size_t)cbase * 8),
                16, 0, 0);
        }
        // ---- B tile: 128x32 f32 -> f16 fused ----
#pragma unroll
        for (int it = 0; it < 4; ++it) {
            const int c4 = it * 256 + tid;
            const int r  = c4 >> 3;
            const int ch = (c4 & 7) << 2;
            int brow = col0 + r;
            if (brow >= N) brow = N - 1;      // rows past N never stored
            const float4 bv = *(const float4*)&B[(size_t)brow * K + k0 + ch];
            f16x4 p;
            p[0] = (_Float16)bv.x; p[1] = (_Float16)bv.y;
            p[2] = (_Float16)bv.z; p[3] = (_Float16)bv.w;
            *(f16x4*)&Bs[r * 32 + ch] = p;
        }
        __syncthreads();

        f16x8 af[4], bfr[4];
#pragma unroll
        for (int mi = 0; mi < 4; ++mi)
            af[mi] = *(const f16x8*)&As[(wr * 64 + mi * 16 + fr) * 32 + ks];
#pragma unroll
        for (int ni = 0; ni < 4; ++ni)
            bfr[ni] = *(const f16x8*)&Bs[(wc * 64 + ni * 16 + fr) * 32 + ks];
#pragma unroll
        for (int mi = 0; mi < 4; ++mi)
#pragma unroll
            for (int ni = 0; ni < 4; ++ni)
                acc[mi][ni] = __builtin_amdgcn_mfma_f32_16x16x32_f16(
                    af[mi], bfr[ni], acc[mi][ni], 0, 0, 0);
    }

    // ---- epilogue via LDS: 2 passes over column halves, coalesced stores ----
#pragma unroll
    for (int p = 0; p < 2; ++p) {
        __syncthreads();
        if (wc == p) {
#pragma unroll
            for (int mi = 0; mi < 4; ++mi)
#pragma unroll
                for (int ni = 0; ni < 4; ++ni) {
                    const f32x4 v = acc[mi][ni];
#pragma unroll
                    for (int r = 0; r < 4; ++r)
                        sh[(wr * 64 + mi * 16 + quad * 4 + r) * CSTR + ni * 16 + fr] =
                            (_Float16)v[r];
                }
        }
        __syncthreads();
#pragma unroll
        for (int it = 0; it < 4; ++it) {
            const int id  = it * 256 + tid;
            const int row = id >> 3;
            const int ch  = (id & 7) * 8;
            const int col = col0 + p * 64 + ch;
            if (col < N) {
                const f16x4 lo = *(const f16x4*)&sh[row * CSTR + ch];
                const f16x4 hi = *(const f16x4*)&sh[row * CSTR + ch + 4];
                if constexpr (sizeof(CT) == 2) {
                    f16x8 v;
                    v[0]=lo[0]; v[1]=lo[1]; v[2]=lo[2]; v[3]=lo[3];
                    v[4]=hi[0]; v[5]=hi[1]; v[6]=hi[2]; v[7]=hi[3];
                    *(f16x8*)&Cp[(size_t)(row0 + row) * N + col] = v;
                } else {
                    float4 v0 = make_float4((float)lo[0], (float)lo[1],
                                            (float)lo[2], (float)lo[3]);
                    float4 v1 = make_float4((float)hi[0], (float)hi[1],
                                            (float)hi[2], (float)hi[3]);
                    *(float4*)&Cp[(size_t)(row0 + row) * N + col]     = v0;
                    *(float4*)&Cp[(size_t)(row0 + row) * N + col + 4] = v1;
                }
            }
        }
    }
}

// ---------------------------------------------------------------------------
// Fused: sum nsplit f16 qkv partials -> rope q,k -> write f16 into partial 0;
// also emit V transposed as vt[d 512][s 1024]. One block per position.
// ---------------------------------------------------------------------------
__global__ __launch_bounds__(256) void rope_reduce(_Float16* __restrict__ parts,
                                                   int nsplit,
                                                   _Float16* __restrict__ vt,
                                                   const int* __restrict__ positions) {
    __shared__ float buf[QKV_N];   // 20 KB
    const int s   = blockIdx.x;
    const int tid = threadIdx.x;
    const size_t PSTR = (size_t)S_LEN * QKV_N;

    for (int c = tid; c < QKV_N / 4; c += 256) {
        float4 a = make_float4(0.f, 0.f, 0.f, 0.f);
        for (int j = 0; j < nsplit; ++j) {
            const f16x4 v = ((const f16x4*)(parts + j * PSTR + (size_t)s * QKV_N))[c];
            a.x += (float)v[0]; a.y += (float)v[1];
            a.z += (float)v[2]; a.w += (float)v[3];
        }
        ((float4*)buf)[c] = a;
    }
    __syncthreads();

    const float pos = (float)positions[s];
    _Float16* orow = parts + (size_t)s * QKV_N;   // write into partial 0
    for (int w = tid; w < 72 * 32; w += 256) {
        const int h = w >> 5;
        const int t = w & 31;
        const float inv_freq = exp2f(-(float)t * (13.287712379549449f / 32.0f));
        const float ang = pos * inv_freq;
        float sn, cs;
        sincosf(ang, &sn, &cs);
        const float x1 = buf[h * 64 + t];
        const float x2 = buf[h * 64 + t + 32];
        orow[h * 64 + t]      = (_Float16)(x1 * cs - x2 * sn);
        orow[h * 64 + t + 32] = (_Float16)(x2 * cs + x1 * sn);
    }
    // V -> vt (transposed), source cols 4608..5119
    for (int c = tid; c < NKV * HD; c += 256)
        vt[(size_t)c * S_LEN + s] = (_Float16)buf[(NH + NKV) * HD + c];
}

// ---------------------------------------------------------------------------
// o-proj partial reduce: out(f32) = sum of nsplit f16 partials
// ---------------------------------------------------------------------------
__global__ __launch_bounds__(256) void o_reduce(const _Float16* __restrict__ parts,
                                                float* __restrict__ out,
                                                int n4, int nsplit) {
    const size_t PSTR = (size_t)S_LEN * HDIM;
    const int stride = gridDim.x * blockDim.x;
    for (int i = blockIdx.x * blockDim.x + threadIdx.x; i < n4; i += stride) {
        float4 a = make_float4(0.f, 0.f, 0.f, 0.f);
        for (int j = 0; j < nsplit; ++j) {
            const f16x4 v = ((const f16x4*)(parts + j * PSTR))[i];
            a.x += (float)v[0]; a.y += (float)v[1];
            a.z += (float)v[2]; a.w += (float)v[3];
        }
        ((float4*)out)[i] = a;
    }
}

// ---------------------------------------------------------------------------
// MFMA flash attention (unchanged from round 4/5).
// ---------------------------------------------------------------------------
#define LSTR 72
__global__ __launch_bounds__(256) void attn_mfma(const _Float16* __restrict__ qkv,
                                                 const _Float16* __restrict__ vt,
                                                 const float* __restrict__ sinks,
                                                 const int* __restrict__ positions,
                                                 _Float16* __restrict__ attn_out) {
    __shared__ __align__(16) _Float16 Ks[64 * LSTR];
    __shared__ __align__(16) _Float16 Vs[64 * LSTR];
    __shared__ __align__(16) _Float16 Ps[64 * LSTR];
    __shared__ int posk[64];

    const int tid  = threadIdx.x;
    const int lane = tid & 63;
    const int wave = tid >> 6;
    const int fr   = lane & 15;
    const int quad = lane >> 4;
    const int ks8  = quad * 8;
    const int n    = blockIdx.x;
    const int qt   = (int)gridDim.y - 1 - (int)blockIdx.y;   // heavy tiles first
    const int g    = n >> 3;

    const _Float16* qrow = qkv + (size_t)(qt * 64 + wave * 16 + fr) * QKV_N + n * HD;
    const f16x8 a_q0 = *(const f16x8*)&qrow[ks8];
    const f16x8 a_q1 = *(const f16x8*)&qrow[32 + ks8];

    int pq[4];
#pragma unroll
    for (int r = 0; r < 4; ++r)
        pq[r] = positions[qt * 64 + wave * 16 + quad * 4 + r];

    const float sinkv = sinks[n];
    float m[4], l[4];
    f32x4 o[4] = {};
#pragma unroll
    for (int r = 0; r < 4; ++r) { m[r] = sinkv; l[r] = 1.0f; }

    for (int kt = 0; kt <= qt; ++kt) {
        __syncthreads();
        const _Float16* Kg = qkv + (size_t)(kt * 64) * QKV_N + NH * HD + g * HD;
        const _Float16* Vg = vt + (size_t)(g * HD) * S_LEN + kt * 64;
#pragma unroll
        for (int it = 0; it < 2; ++it) {
            const int c = it * 256 + tid;
            const int r = c >> 3, off8 = (c & 7) * 8;
            const f16x8 kv = *(const f16x8*)&Kg[(size_t)r * QKV_N + off8];
            *(f16x8*)&Ks[r * LSTR + off8] = kv;
            const f16x8 vv = *(const f16x8*)&Vg[(size_t)r * S_LEN + off8];
            *(f16x8*)&Vs[r * LSTR + off8] = vv;
        }
        if (tid < 64) posk[tid] = positions[kt * 64 + tid];
        __syncthreads();

        // ---- S = Q K^T ----
        f32x4 s[4] = {};
#pragma unroll
        for (int nt = 0; nt < 4; ++nt) {
            const f16x8 b0 = *(const f16x8*)&Ks[(nt * 16 + fr) * LSTR + ks8];
            s[nt] = __builtin_amdgcn_mfma_f32_16x16x32_f16(a_q0, b0, s[nt], 0, 0, 0);
            const f16x8 b1 = *(const f16x8*)&Ks[(nt * 16 + fr) * LSTR + 32 + ks8];
            s[nt] = __builtin_amdgcn_mfma_f32_16x16x32_f16(a_q1, b1, s[nt], 0, 0, 0);
        }

        const bool diag = (kt == qt);
        int pk[4];
        if (diag) {
#pragma unroll
            for (int nt = 0; nt < 4; ++nt) pk[nt] = posk[nt * 16 + fr];
        }
#pragma unroll
        for (int nt = 0; nt < 4; ++nt)
#pragma unroll
            for (int r = 0; r < 4; ++r) {
                float sv = s[nt][r] * SCALE;
                if (diag && pk[nt] > pq[r]) sv = -3.0e38f;
                s[nt][r] = sv;
            }

#pragma unroll
        for (int r = 0; r < 4; ++r) {
            float tm = fmaxf(fmaxf(s[0][r], s[1][r]), fmaxf(s[2][r], s[3][r]));
            tm = fmaxf(tm, __shfl_xor(tm, 1, 64));
            tm = fmaxf(tm, __shfl_xor(tm, 2, 64));
            tm = fmaxf(tm, __shfl_xor(tm, 4, 64));
            tm = fmaxf(tm, __shfl_xor(tm, 8, 64));
            const float nm = fmaxf(m[r], tm);
            const float alpha = __expf(m[r] - nm);
            float rs = 0.0f;
#pragma unroll
            for (int nt = 0; nt < 4; ++nt) {
                const float p = __expf(s[nt][r] - nm);
                s[nt][r] = p;
                rs += p;
            }
            rs += __shfl_xor(rs, 1, 64);
            rs += __shfl_xor(rs, 2, 64);
            rs += __shfl_xor(rs, 4, 64);
            rs += __shfl_xor(rs, 8, 64);
            l[r] = l[r] * alpha + rs;
            m[r] = nm;
#pragma unroll
            for (int nt = 0; nt < 4; ++nt) o[nt][r] *= alpha;
        }

#pragma unroll
        for (int nt = 0; nt < 4; ++nt)
#pragma unroll
            for (int r = 0; r < 4; ++r)
                Ps[(wave * 16 + quad * 4 + r) * LSTR + nt * 16 + fr] = (_Float16)s[nt][r];
        __threadfence_block();

#pragma unroll
        for (int k2 = 0; k2 < 2; ++k2) {
            const f16x8 ap = *(const f16x8*)&Ps[(wave * 16 + fr) * LSTR + k2 * 32 + ks8];
#pragma unroll
            for (int nt = 0; nt < 4; ++nt) {
                const f16x8 bv = *(const f16x8*)&Vs[(nt * 16 + fr) * LSTR + k2 * 32 + ks8];
                o[nt] = __builtin_amdgcn_mfma_f32_16x16x32_f16(ap, bv, o[nt], 0, 0, 0);
            }
        }
    }

#pragma unroll
    for (int r = 0; r < 4; ++r) {
        const float inv = 1.0f / l[r];
        const size_t row = (size_t)(qt * 64 + wave * 16 + quad * 4 + r);
#pragma unroll
        for (int nt = 0; nt < 4; ++nt)
            attn_out[row * O_K + n * HD + nt * 16 + fr] = (_Float16)(o[nt][r] * inv);
    }
}

// ---------------------------------------------------------------------------
extern "C" void kernel_launch(void* const* d_in, const int* in_sizes, int n_in,
                              void* d_out, int out_size, void* d_ws, size_t ws_size,
                              hipStream_t stream) {
    const int*   positions = (const int*)d_in[0];
    const float* hidden    = (const float*)d_in[1];   // (1024, 2880)
    const float* qkv_w     = (const float*)d_in[2];   // (5120, 2880)
    const float* o_w       = (const float*)d_in[3];   // (2880, 4096)
    const float* sinks     = (const float*)d_in[4];   // (64,)
    float* out = (float*)d_out;                       // (1024, 2880)

    const size_t n_hid  = (size_t)S_LEN * HDIM;       //  2,949,120
    const size_t n_qkv  = (size_t)S_LEN * QKV_N;      //  5,242,880
    const size_t n_attn = (size_t)S_LEN * O_K;        //  4,194,304
    const size_t n_vt   = (size_t)NKV * HD * S_LEN;   //    524,288
    const size_t n_out  = (size_t)S_LEN * HDIM;       //  2,949,120

    const int SP_Q = 6;   // 2880/6 = 480 = 15 BK-steps, 1920 blocks
    const int SP_O = 8;   // 4096/8 = 512 = 16 BK-steps, 1472 blocks

    // layout: hid | qkvp (SP_Q planes; plane0 = roped qkv; also reused as
    // opart after attention) | attn | vt
    const size_t need = (n_hid + SP_Q * n_qkv + n_attn + n_vt) * sizeof(_Float16);

    if (ws_size >= need) {
        _Float16* hid_h  = (_Float16*)d_ws;
        _Float16* qkvp   = hid_h + n_hid;
        _Float16* attn_h = qkvp + SP_Q * n_qkv;
        _Float16* vt     = attn_h + n_attn;
        _Float16* opart  = qkvp;   // SP_O * n_out = 23.6M <= SP_Q * n_qkv = 31.5M

        cvt_f32_f16<<<512, 256, 0, stream>>>(hidden, hid_h, (int)(n_hid / 4));
        gemm_f16<_Float16><<<dim3(QKV_N / 128, S_LEN / 128, SP_Q), 256, 0, stream>>>(
            hid_h, qkv_w, qkvp, S_LEN, QKV_N, HDIM);
        rope_reduce<<<S_LEN, 256, 0, stream>>>(qkvp, SP_Q, vt, positions);
        attn_mfma<<<dim3(NH, S_LEN / 64), 256, 0, stream>>>(qkvp, vt, sinks, positions, attn_h);
        gemm_f16<_Float16><<<dim3((HDIM + 127) / 128, S_LEN / 128, SP_O), 256, 0, stream>>>(
            attn_h, o_w, opart, S_LEN, HDIM, O_K);
        o_reduce<<<1024, 256, 0, stream>>>(opart, out, (int)(n_out / 4), SP_O);
    } else {
        // minimal workspace: no split-K, o-proj writes f32 out directly
        _Float16* hid_h  = (_Float16*)d_ws;
        _Float16* qkvp   = hid_h + n_hid;
        _Float16* attn_h = qkvp + n_qkv;
        _Float16* vt     = attn_h + n_attn;

        cvt_f32_f16<<<512, 256, 0, stream>>>(hidden, hid_h, (int)(n_hid / 4));
        gemm_f16<_Float16><<<dim3(QKV_N / 128, S_LEN / 128, 1), 256, 0, stream>>>(
            hid_h, qkv_w, qkvp, S_LEN, QKV_N, HDIM);
        rope_reduce<<<S_LEN, 256, 0, stream>>>(qkvp, 1, vt, positions);
        attn_mfma<<<dim3(NH, S_LEN / 64), 256, 0, stream>>>(qkvp, vt, sinks, positions, attn_h);
        gemm_f16<float><<<dim3((HDIM + 127) / 128, S_LEN / 128, 1), 256, 0, stream>>>(
            attn_h, o_w, out, S_LEN, HDIM, O_K);
    }
}

// Round 7
// 304.629 us; speedup vs baseline: 1.0864x; 1.0864x over previous
//
#include <hip/hip_runtime.h>
#include <hip/hip_bf16.h>
#include <math.h>

// Problem constants
#define S_LEN 1024
#define HDIM  2880
#define NH    64
#define NKV   8
#define HD    64
#define QKV_N ((NH + 2*NKV) * HD)   // 5120
#define O_K   (NH * HD)             // 4096
#define SCALE 0.125f                // HD^-0.5

typedef _Float16 f16x8 __attribute__((ext_vector_type(8)));
typedef _Float16 f16x4 __attribute__((ext_vector_type(4)));
typedef float    f32x4 __attribute__((ext_vector_type(4)));

// ---------------------------------------------------------------------------
// f32 -> f16 convert (hidden only; n4 = float4 count)
// ---------------------------------------------------------------------------
__global__ __launch_bounds__(256) void cvt_f32_f16(const float* __restrict__ src,
                                                   _Float16* __restrict__ dst, int n4) {
    const int stride = gridDim.x * blockDim.x;
    for (int i = blockIdx.x * blockDim.x + threadIdx.x; i < n4; i += stride) {
        const float4 v = ((const float4*)src)[i];
        f16x4 p;
        p[0] = (_Float16)v.x; p[1] = (_Float16)v.y;
        p[2] = (_Float16)v.z; p[3] = (_Float16)v.w;
        ((f16x4*)dst)[i] = p;
    }
}

// ---------------------------------------------------------------------------
// Split-K MFMA GEMM, single-barrier double-buffered K-loop.
// Cpart[z][M,N] = A[M,K slice](f16) * B[N,K](f32, fused cvt)^T
// 128x128 tile, BK=32, 256 thr = 4 waves (64x64 quadrant, 4x4 MFMAs).
// Per step: barrier -> issue next A-DMA + next B loads -> compute cur ->
// cvt+ds_write next B. vmcnt(0) at the NEXT barrier lands after a full
// compute phase. Epilogue via LDS for coalesced 16B stores.
// ---------------------------------------------------------------------------
#define CSTR 68
template<typename CT>
__global__ __launch_bounds__(256) void gemm_f16(const _Float16* __restrict__ A,
                                                const float* __restrict__ B,
                                                CT* __restrict__ C,
                                                int M, int N, int K) {
    __shared__ __align__(16) _Float16 sh[16384];   // 32 KB: As0|As1|Bs0|Bs1

    const int tid  = threadIdx.x;
    const int lane = tid & 63;
    const int wave = tid >> 6;
    const int wr   = wave >> 1;
    const int wc   = wave & 1;
    const int quad = lane >> 4;
    const int fr   = lane & 15;
    const int ks   = quad * 8;
    const int row0 = blockIdx.y * 128;
    const int col0 = blockIdx.x * 128;

    const int klen   = K / (int)gridDim.z;
    const int kb     = (int)blockIdx.z * klen;
    const int nsteps = klen / 32;
    CT* Cp = C + (size_t)blockIdx.z * M * N;

    // A loader mapping (2 DMA chunks / thread)
    const int a_cbase0 = wave * 64;
    const int a_ci0 = a_cbase0 + lane;
    const int a_r0 = a_ci0 >> 2, a_ch0 = a_ci0 & 3;
    const int a_cbase1 = 256 + wave * 64;
    const int a_ci1 = a_cbase1 + lane;
    const int a_r1 = a_ci1 >> 2, a_ch1 = a_ci1 & 3;
    // B loader mapping (4 float4 / thread)
    int b_r[4], b_ch[4];
#pragma unroll
    for (int it = 0; it < 4; ++it) {
        const int c4 = it * 256 + tid;
        b_r[it]  = c4 >> 3;
        b_ch[it] = (c4 & 7) << 2;
    }

    float4 breg[4];
    f32x4 acc[4][4] = {};

    // ---- prologue: stage tile 0 ----
    {
        const _Float16* gp0 = A + (size_t)(row0 + a_r0) * K + kb + a_ch0 * 8;
        __builtin_amdgcn_global_load_lds(
            (const __attribute__((address_space(1))) void*)gp0,
            (__attribute__((address_space(3))) void*)(sh + (size_t)a_cbase0 * 8), 16, 0, 0);
        const _Float16* gp1 = A + (size_t)(row0 + a_r1) * K + kb + a_ch1 * 8;
        __builtin_amdgcn_global_load_lds(
            (const __attribute__((address_space(1))) void*)gp1,
            (__attribute__((address_space(3))) void*)(sh + (size_t)a_cbase1 * 8), 16, 0, 0);
#pragma unroll
        for (int it = 0; it < 4; ++it) {
            int brow = col0 + b_r[it];
            if (brow >= N) brow = N - 1;
            breg[it] = *(const float4*)&B[(size_t)brow * K + kb + b_ch[it]];
        }
        _Float16* Bs0 = sh + 8192;
#pragma unroll
        for (int it = 0; it < 4; ++it) {
            f16x4 p;
            p[0] = (_Float16)breg[it].x; p[1] = (_Float16)breg[it].y;
            p[2] = (_Float16)breg[it].z; p[3] = (_Float16)breg[it].w;
            *(f16x4*)&Bs0[b_r[it] * 32 + b_ch[it]] = p;
        }
    }

    for (int step = 0; step < nsteps; ++step) {
        const int cur = step & 1;
        const int nxt = cur ^ 1;
        _Float16* Acur = sh + cur * 4096;
        _Float16* Anxt = sh + nxt * 4096;
        _Float16* Bcur = sh + 8192 + cur * 4096;
        _Float16* Bnxt = sh + 8192 + nxt * 4096;

        __syncthreads();   // tile[cur] ready (drains prev DMA + ds_writes)

        const bool more = (step + 1 < nsteps);
        if (more) {
            const int k1 = kb + (step + 1) * 32;
            const _Float16* gp0 = A + (size_t)(row0 + a_r0) * K + k1 + a_ch0 * 8;
            __builtin_amdgcn_global_load_lds(
                (const __attribute__((address_space(1))) void*)gp0,
                (__attribute__((address_space(3))) void*)(Anxt + (size_t)a_cbase0 * 8), 16, 0, 0);
            const _Float16* gp1 = A + (size_t)(row0 + a_r1) * K + k1 + a_ch1 * 8;
            __builtin_amdgcn_global_load_lds(
                (const __attribute__((address_space(1))) void*)gp1,
                (__attribute__((address_space(3))) void*)(Anxt + (size_t)a_cbase1 * 8), 16, 0, 0);
#pragma unroll
            for (int it = 0; it < 4; ++it) {
                int brow = col0 + b_r[it];
                if (brow >= N) brow = N - 1;
                breg[it] = *(const float4*)&B[(size_t)brow * K + k1 + b_ch[it]];
            }
        }

        // ---- compute tile[cur] ----
        f16x8 af[4], bfr[4];
#pragma unroll
        for (int mi = 0; mi < 4; ++mi)
            af[mi] = *(const f16x8*)&Acur[(wr * 64 + mi * 16 + fr) * 32 + ks];
#pragma unroll
        for (int ni = 0; ni < 4; ++ni)
            bfr[ni] = *(const f16x8*)&Bcur[(wc * 64 + ni * 16 + fr) * 32 + ks];
#pragma unroll
        for (int mi = 0; mi < 4; ++mi)
#pragma unroll
            for (int ni = 0; ni < 4; ++ni)
                acc[mi][ni] = __builtin_amdgcn_mfma_f32_16x16x32_f16(
                    af[mi], bfr[ni], acc[mi][ni], 0, 0, 0);

        if (more) {
#pragma unroll
            for (int it = 0; it < 4; ++it) {
                f16x4 p;
                p[0] = (_Float16)breg[it].x; p[1] = (_Float16)breg[it].y;
                p[2] = (_Float16)breg[it].z; p[3] = (_Float16)breg[it].w;
                *(f16x4*)&Bnxt[b_r[it] * 32 + b_ch[it]] = p;
            }
        }
    }

    // ---- epilogue via LDS: 2 passes over column halves, coalesced stores ----
#pragma unroll
    for (int p = 0; p < 2; ++p) {
        __syncthreads();
        if (wc == p) {
#pragma unroll
            for (int mi = 0; mi < 4; ++mi)
#pragma unroll
                for (int ni = 0; ni < 4; ++ni) {
                    const f32x4 v = acc[mi][ni];
#pragma unroll
                    for (int r = 0; r < 4; ++r)
                        sh[(wr * 64 + mi * 16 + quad * 4 + r) * CSTR + ni * 16 + fr] =
                            (_Float16)v[r];
                }
        }
        __syncthreads();
#pragma unroll
        for (int it = 0; it < 4; ++it) {
            const int id  = it * 256 + tid;
            const int row = id >> 3;
            const int ch  = (id & 7) * 8;
            const int col = col0 + p * 64 + ch;
            if (col < N) {
                const f16x4 lo = *(const f16x4*)&sh[row * CSTR + ch];
                const f16x4 hi = *(const f16x4*)&sh[row * CSTR + ch + 4];
                if constexpr (sizeof(CT) == 2) {
                    f16x8 v;
                    v[0]=lo[0]; v[1]=lo[1]; v[2]=lo[2]; v[3]=lo[3];
                    v[4]=hi[0]; v[5]=hi[1]; v[6]=hi[2]; v[7]=hi[3];
                    *(f16x8*)&Cp[(size_t)(row0 + row) * N + col] = v;
                } else {
                    float4 v0 = make_float4((float)lo[0], (float)lo[1],
                                            (float)lo[2], (float)lo[3]);
                    float4 v1 = make_float4((float)hi[0], (float)hi[1],
                                            (float)hi[2], (float)hi[3]);
                    *(float4*)&Cp[(size_t)(row0 + row) * N + col]     = v0;
                    *(float4*)&Cp[(size_t)(row0 + row) * N + col + 4] = v1;
                }
            }
        }
    }
}

// ---------------------------------------------------------------------------
// Fused: sum nsplit f16 qkv partials -> rope q,k -> write f16 into partial 0;
// also emit V transposed as vt[d 512][s 1024]. One block per position.
// ---------------------------------------------------------------------------
__global__ __launch_bounds__(256) void rope_reduce(_Float16* __restrict__ parts,
                                                   int nsplit,
                                                   _Float16* __restrict__ vt,
                                                   const int* __restrict__ positions) {
    __shared__ float buf[QKV_N];   // 20 KB
    const int s   = blockIdx.x;
    const int tid = threadIdx.x;
    const size_t PSTR = (size_t)S_LEN * QKV_N;

    for (int c = tid; c < QKV_N / 4; c += 256) {
        float4 a = make_float4(0.f, 0.f, 0.f, 0.f);
        for (int j = 0; j < nsplit; ++j) {
            const f16x4 v = ((const f16x4*)(parts + j * PSTR + (size_t)s * QKV_N))[c];
            a.x += (float)v[0]; a.y += (float)v[1];
            a.z += (float)v[2]; a.w += (float)v[3];
        }
        ((float4*)buf)[c] = a;
    }
    __syncthreads();

    const float pos = (float)positions[s];
    _Float16* orow = parts + (size_t)s * QKV_N;   // write into partial 0
    for (int w = tid; w < 72 * 32; w += 256) {
        const int h = w >> 5;
        const int t = w & 31;
        const float inv_freq = exp2f(-(float)t * (13.287712379549449f / 32.0f));
        const float ang = pos * inv_freq;
        float sn, cs;
        sincosf(ang, &sn, &cs);
        const float x1 = buf[h * 64 + t];
        const float x2 = buf[h * 64 + t + 32];
        orow[h * 64 + t]      = (_Float16)(x1 * cs - x2 * sn);
        orow[h * 64 + t + 32] = (_Float16)(x2 * cs + x1 * sn);
    }
    // V -> vt (transposed), source cols 4608..5119
    for (int c = tid; c < NKV * HD; c += 256)
        vt[(size_t)c * S_LEN + s] = (_Float16)buf[(NH + NKV) * HD + c];
}

// ---------------------------------------------------------------------------
// o-proj partial reduce: out(f32) = sum of nsplit f16 partials
// ---------------------------------------------------------------------------
__global__ __launch_bounds__(256) void o_reduce(const _Float16* __restrict__ parts,
                                                float* __restrict__ out,
                                                int n4, int nsplit) {
    const size_t PSTR = (size_t)S_LEN * HDIM;
    const int stride = gridDim.x * blockDim.x;
    for (int i = blockIdx.x * blockDim.x + threadIdx.x; i < n4; i += stride) {
        float4 a = make_float4(0.f, 0.f, 0.f, 0.f);
        for (int j = 0; j < nsplit; ++j) {
            const f16x4 v = ((const f16x4*)(parts + j * PSTR))[i];
            a.x += (float)v[0]; a.y += (float)v[1];
            a.z += (float)v[2]; a.w += (float)v[3];
        }
        ((float4*)out)[i] = a;
    }
}

// ---------------------------------------------------------------------------
// MFMA flash attention, double-buffered K/V staging (single barrier / tile).
// Block = 256 thr = 4 waves per (head n, 64-q tile). Wave w owns rows
// [16w,16w+16). Q A-frags from global (regs). K [kk][d]; V pre-transposed
// [d][kk] from vt. P via wave-private LDS rows. Diag mask reads positions
// directly (non-diag tiles rely on monotone positions).
// ---------------------------------------------------------------------------
#define LSTR 72
__global__ __launch_bounds__(256) void attn_mfma(const _Float16* __restrict__ qkv,
                                                 const _Float16* __restrict__ vt,
                                                 const float* __restrict__ sinks,
                                                 const int* __restrict__ positions,
                                                 _Float16* __restrict__ attn_out) {
    __shared__ __align__(16) _Float16 Ks[2][64 * LSTR];
    __shared__ __align__(16) _Float16 Vs[2][64 * LSTR];
    __shared__ __align__(16) _Float16 Ps[64 * LSTR];

    const int tid  = threadIdx.x;
    const int lane = tid & 63;
    const int wave = tid >> 6;
    const int fr   = lane & 15;
    const int quad = lane >> 4;
    const int ks8  = quad * 8;
    const int n    = blockIdx.x;
    const int qt   = (int)gridDim.y - 1 - (int)blockIdx.y;   // heavy tiles first
    const int g    = n >> 3;

    // staging mapping: 2 chunks of 8 f16 per thread
    int st_r[2], st_o[2];
#pragma unroll
    for (int it = 0; it < 2; ++it) {
        const int c = it * 256 + tid;
        st_r[it] = c >> 3;
        st_o[it] = (c & 7) * 8;
    }

    const _Float16* qrow = qkv + (size_t)(qt * 64 + wave * 16 + fr) * QKV_N + n * HD;
    const f16x8 a_q0 = *(const f16x8*)&qrow[ks8];
    const f16x8 a_q1 = *(const f16x8*)&qrow[32 + ks8];

    int pq[4];
#pragma unroll
    for (int r = 0; r < 4; ++r)
        pq[r] = positions[qt * 64 + wave * 16 + quad * 4 + r];

    const float sinkv = sinks[n];
    float m[4], l[4];
    f32x4 o[4] = {};
#pragma unroll
    for (int r = 0; r < 4; ++r) { m[r] = sinkv; l[r] = 1.0f; }

    f16x8 kreg[2], vreg[2];
    // ---- prologue: stage tile 0 ----
    {
        const _Float16* Kg = qkv + (size_t)0 * QKV_N + NH * HD + g * HD;
        const _Float16* Vg = vt + (size_t)(g * HD) * S_LEN;
#pragma unroll
        for (int it = 0; it < 2; ++it) {
            kreg[it] = *(const f16x8*)&Kg[(size_t)st_r[it] * QKV_N + st_o[it]];
            vreg[it] = *(const f16x8*)&Vg[(size_t)st_r[it] * S_LEN + st_o[it]];
        }
#pragma unroll
        for (int it = 0; it < 2; ++it) {
            *(f16x8*)&Ks[0][st_r[it] * LSTR + st_o[it]] = kreg[it];
            *(f16x8*)&Vs[0][st_r[it] * LSTR + st_o[it]] = vreg[it];
        }
    }

    for (int kt = 0; kt <= qt; ++kt) {
        const int cur = kt & 1;
        const int nxt = cur ^ 1;
        __syncthreads();   // tile[cur] staged

        const bool more = (kt < qt);
        if (more) {
            const _Float16* Kg = qkv + (size_t)((kt + 1) * 64) * QKV_N + NH * HD + g * HD;
            const _Float16* Vg = vt + (size_t)(g * HD) * S_LEN + (kt + 1) * 64;
#pragma unroll
            for (int it = 0; it < 2; ++it) {
                kreg[it] = *(const f16x8*)&Kg[(size_t)st_r[it] * QKV_N + st_o[it]];
                vreg[it] = *(const f16x8*)&Vg[(size_t)st_r[it] * S_LEN + st_o[it]];
            }
        }

        // ---- S = Q K^T ----
        f32x4 s[4] = {};
#pragma unroll
        for (int nt = 0; nt < 4; ++nt) {
            const f16x8 b0 = *(const f16x8*)&Ks[cur][(nt * 16 + fr) * LSTR + ks8];
            s[nt] = __builtin_amdgcn_mfma_f32_16x16x32_f16(a_q0, b0, s[nt], 0, 0, 0);
            const f16x8 b1 = *(const f16x8*)&Ks[cur][(nt * 16 + fr) * LSTR + 32 + ks8];
            s[nt] = __builtin_amdgcn_mfma_f32_16x16x32_f16(a_q1, b1, s[nt], 0, 0, 0);
        }

        // ---- scale + causal mask (diag tile only) ----
        const bool diag = (kt == qt);
        int pk[4];
        if (diag) {
#pragma unroll
            for (int nt = 0; nt < 4; ++nt) pk[nt] = positions[qt * 64 + nt * 16 + fr];
        }
#pragma unroll
        for (int nt = 0; nt < 4; ++nt)
#pragma unroll
            for (int r = 0; r < 4; ++r) {
                float sv = s[nt][r] * SCALE;
                if (diag && pk[nt] > pq[r]) sv = -3.0e38f;
                s[nt][r] = sv;
            }

        // ---- online softmax per row ----
#pragma unroll
        for (int r = 0; r < 4; ++r) {
            float tm = fmaxf(fmaxf(s[0][r], s[1][r]), fmaxf(s[2][r], s[3][r]));
            tm = fmaxf(tm, __shfl_xor(tm, 1, 64));
            tm = fmaxf(tm, __shfl_xor(tm, 2, 64));
            tm = fmaxf(tm, __shfl_xor(tm, 4, 64));
            tm = fmaxf(tm, __shfl_xor(tm, 8, 64));
            const float nm = fmaxf(m[r], tm);
            const float alpha = __expf(m[r] - nm);
            float rs = 0.0f;
#pragma unroll
            for (int nt = 0; nt < 4; ++nt) {
                const float p = __expf(s[nt][r] - nm);
                s[nt][r] = p;
                rs += p;
            }
            rs += __shfl_xor(rs, 1, 64);
            rs += __shfl_xor(rs, 2, 64);
            rs += __shfl_xor(rs, 4, 64);
            rs += __shfl_xor(rs, 8, 64);
            l[r] = l[r] * alpha + rs;
            m[r] = nm;
#pragma unroll
            for (int nt = 0; nt < 4; ++nt) o[nt][r] *= alpha;
        }

        // ---- P -> wave-private LDS rows ----
#pragma unroll
        for (int nt = 0; nt < 4; ++nt)
#pragma unroll
            for (int r = 0; r < 4; ++r)
                Ps[(wave * 16 + quad * 4 + r) * LSTR + nt * 16 + fr] = (_Float16)s[nt][r];
        __threadfence_block();

        // ---- O += P V ----
#pragma unroll
        for (int k2 = 0; k2 < 2; ++k2) {
            const f16x8 ap = *(const f16x8*)&Ps[(wave * 16 + fr) * LSTR + k2 * 32 + ks8];
#pragma unroll
            for (int nt = 0; nt < 4; ++nt) {
                const f16x8 bv = *(const f16x8*)&Vs[cur][(nt * 16 + fr) * LSTR + k2 * 32 + ks8];
                o[nt] = __builtin_amdgcn_mfma_f32_16x16x32_f16(ap, bv, o[nt], 0, 0, 0);
            }
        }

        if (more) {
#pragma unroll
            for (int it = 0; it < 2; ++it) {
                *(f16x8*)&Ks[nxt][st_r[it] * LSTR + st_o[it]] = kreg[it];
                *(f16x8*)&Vs[nxt][st_r[it] * LSTR + st_o[it]] = vreg[it];
            }
        }
    }

    // ---- epilogue ----
#pragma unroll
    for (int r = 0; r < 4; ++r) {
        const float inv = 1.0f / l[r];
        const size_t row = (size_t)(qt * 64 + wave * 16 + quad * 4 + r);
#pragma unroll
        for (int nt = 0; nt < 4; ++nt)
            attn_out[row * O_K + n * HD + nt * 16 + fr] = (_Float16)(o[nt][r] * inv);
    }
}

// ---------------------------------------------------------------------------
extern "C" void kernel_launch(void* const* d_in, const int* in_sizes, int n_in,
                              void* d_out, int out_size, void* d_ws, size_t ws_size,
                              hipStream_t stream) {
    const int*   positions = (const int*)d_in[0];
    const float* hidden    = (const float*)d_in[1];   // (1024, 2880)
    const float* qkv_w     = (const float*)d_in[2];   // (5120, 2880)
    const float* o_w       = (const float*)d_in[3];   // (2880, 4096)
    const float* sinks     = (const float*)d_in[4];   // (64,)
    float* out = (float*)d_out;                       // (1024, 2880)

    const size_t n_hid  = (size_t)S_LEN * HDIM;       //  2,949,120
    const size_t n_qkv  = (size_t)S_LEN * QKV_N;      //  5,242,880
    const size_t n_attn = (size_t)S_LEN * O_K;        //  4,194,304
    const size_t n_vt   = (size_t)NKV * HD * S_LEN;   //    524,288
    const size_t n_out  = (size_t)S_LEN * HDIM;       //  2,949,120

    const int SP_Q = 3;   // 2880/3 = 960 = 30 BK-steps, 960 blocks
    const int SP_O = 4;   // 4096/4 = 1024 = 32 BK-steps, 736 blocks

    const size_t need = (n_hid + SP_Q * n_qkv + n_attn + n_vt) * sizeof(_Float16);

    if (ws_size >= need) {
        _Float16* hid_h  = (_Float16*)d_ws;
        _Float16* qkvp   = hid_h + n_hid;
        _Float16* attn_h = qkvp + SP_Q * n_qkv;
        _Float16* vt     = attn_h + n_attn;
        _Float16* opart  = qkvp;   // SP_O*n_out = 11.8M <= SP_Q*n_qkv = 15.7M

        cvt_f32_f16<<<512, 256, 0, stream>>>(hidden, hid_h, (int)(n_hid / 4));
        gemm_f16<_Float16><<<dim3(QKV_N / 128, S_LEN / 128, SP_Q), 256, 0, stream>>>(
            hid_h, qkv_w, qkvp, S_LEN, QKV_N, HDIM);
        rope_reduce<<<S_LEN, 256, 0, stream>>>(qkvp, SP_Q, vt, positions);
        attn_mfma<<<dim3(NH, S_LEN / 64), 256, 0, stream>>>(qkvp, vt, sinks, positions, attn_h);
        gemm_f16<_Float16><<<dim3((HDIM + 127) / 128, S_LEN / 128, SP_O), 256, 0, stream>>>(
            attn_h, o_w, opart, S_LEN, HDIM, O_K);
        o_reduce<<<1024, 256, 0, stream>>>(opart, out, (int)(n_out / 4), SP_O);
    } else {
        // minimal workspace: no split-K, o-proj writes f32 out directly
        _Float16* hid_h  = (_Float16*)d_ws;
        _Float16* qkvp   = hid_h + n_hid;
        _Float16* attn_h = qkvp + n_qkv;
        _Float16* vt     = attn_h + n_attn;

        cvt_f32_f16<<<512, 256, 0, stream>>>(hidden, hid_h, (int)(n_hid / 4));
        gemm_f16<_Float16><<<dim3(QKV_N / 128, S_LEN / 128, 1), 256, 0, stream>>>(
            hid_h, qkv_w, qkvp, S_LEN, QKV_N, HDIM);
        rope_reduce<<<S_LEN, 256, 0, stream>>>(qkvp, 1, vt, positions);
        attn_mfma<<<dim3(NH, S_LEN / 64), 256, 0, stream>>>(qkvp, vt, sinks, positions, attn_h);
        gemm_f16<float><<<dim3((HDIM + 127) / 128, S_LEN / 128, 1), 256, 0, stream>>>(
            attn_h, o_w, out, S_LEN, HDIM, O_K);
    }
}